// Round 1
// baseline (457.315 us; speedup 1.0000x reference)
//
#include <hip/hip_runtime.h>

constexpr int DIM  = 33;
constexpr int DIM2 = DIM * DIM;      // 1089
constexpr int DIM3 = DIM * DIM * DIM; // 35937
constexpr int HW   = 1024 * 1024;
constexpr int BATCH = 8;

__global__ __launch_bounds__(256) void lut3d_apply_kernel(
    const float* __restrict__ lut,   // (3, 33, 33, 33)
    const float* __restrict__ x,     // (8, 3, 1024, 1024)
    float* __restrict__ out)         // (8, 3, 1024, 1024)
{
    const float binsize = 1.000001f / (float)(DIM - 1);

    const int groups_per_img = HW / 4;           // float4 groups per channel plane
    int tid = blockIdx.x * blockDim.x + threadIdx.x;
    if (tid >= BATCH * groups_per_img) return;

    int b = tid / groups_per_img;
    int q = tid - b * groups_per_img;

    const float4* xr = reinterpret_cast<const float4*>(x + (size_t)(b * 3 + 0) * HW);
    const float4* xg = reinterpret_cast<const float4*>(x + (size_t)(b * 3 + 1) * HW);
    const float4* xb = reinterpret_cast<const float4*>(x + (size_t)(b * 3 + 2) * HW);

    float4 rv = xr[q];
    float4 gv = xg[q];
    float4 bv = xb[q];

    float rr[4] = {rv.x, rv.y, rv.z, rv.w};
    float gg[4] = {gv.x, gv.y, gv.z, gv.w};
    float bb[4] = {bv.x, bv.y, bv.z, bv.w};
    float o0[4], o1[4], o2[4];

    const float* L0 = lut;
    const float* L1 = lut + DIM3;
    const float* L2 = lut + 2 * DIM3;

#pragma unroll
    for (int i = 0; i < 4; ++i) {
        float tr = rr[i] / binsize;
        float tg = gg[i] / binsize;
        float tb = bb[i] / binsize;

        int ri = (int)floorf(tr);
        int gi = (int)floorf(tg);
        int bi = (int)floorf(tb);
        ri = ri < 0 ? 0 : (ri > DIM - 2 ? DIM - 2 : ri);
        gi = gi < 0 ? 0 : (gi > DIM - 2 ? DIM - 2 : gi);
        bi = bi < 0 ? 0 : (bi > DIM - 2 ? DIM - 2 : bi);

        float rd = tr - (float)ri;
        float gd = tg - (float)gi;
        float bd = tb - (float)bi;

        int base = bi * DIM2 + gi * DIM + ri;

        float wr0 = 1.0f - rd, wr1 = rd;
        float w00 = (1.0f - bd) * (1.0f - gd);
        float w01 = (1.0f - bd) * gd;
        float w10 = bd * (1.0f - gd);
        float w11 = bd * gd;

        int i00 = base;
        int i01 = base + DIM;
        int i10 = base + DIM2;
        int i11 = base + DIM2 + DIM;

        o0[i] = w00 * (wr0 * L0[i00] + wr1 * L0[i00 + 1])
              + w01 * (wr0 * L0[i01] + wr1 * L0[i01 + 1])
              + w10 * (wr0 * L0[i10] + wr1 * L0[i10 + 1])
              + w11 * (wr0 * L0[i11] + wr1 * L0[i11 + 1]);

        o1[i] = w00 * (wr0 * L1[i00] + wr1 * L1[i00 + 1])
              + w01 * (wr0 * L1[i01] + wr1 * L1[i01 + 1])
              + w10 * (wr0 * L1[i10] + wr1 * L1[i10 + 1])
              + w11 * (wr0 * L1[i11] + wr1 * L1[i11 + 1]);

        o2[i] = w00 * (wr0 * L2[i00] + wr1 * L2[i00 + 1])
              + w01 * (wr0 * L2[i01] + wr1 * L2[i01 + 1])
              + w10 * (wr0 * L2[i10] + wr1 * L2[i10 + 1])
              + w11 * (wr0 * L2[i11] + wr1 * L2[i11 + 1]);
    }

    float4* outr = reinterpret_cast<float4*>(out + (size_t)(b * 3 + 0) * HW);
    float4* outg = reinterpret_cast<float4*>(out + (size_t)(b * 3 + 1) * HW);
    float4* outb = reinterpret_cast<float4*>(out + (size_t)(b * 3 + 2) * HW);

    outr[q] = make_float4(o0[0], o0[1], o0[2], o0[3]);
    outg[q] = make_float4(o1[0], o1[1], o1[2], o1[3]);
    outb[q] = make_float4(o2[0], o2[1], o2[2], o2[3]);
}

extern "C" void kernel_launch(void* const* d_in, const int* in_sizes, int n_in,
                              void* d_out, int out_size, void* d_ws, size_t ws_size,
                              hipStream_t stream) {
    const float* lut = (const float*)d_in[0];  // 3*33*33*33
    const float* x   = (const float*)d_in[1];  // 8*3*1024*1024
    float* out = (float*)d_out;

    int n_groups = BATCH * (HW / 4);           // 2,097,152 threads
    int block = 256;
    int grid = (n_groups + block - 1) / block; // 8192 blocks
    lut3d_apply_kernel<<<grid, block, 0, stream>>>(lut, x, out);
}

// Round 2
// 200.789 us; speedup vs baseline: 2.2776x; 2.2776x over previous
//
#include <hip/hip_runtime.h>

constexpr int DIM  = 33;
constexpr int DIM2 = DIM * DIM;        // 1089
constexpr int DIM3 = DIM * DIM * DIM;  // 35937
constexpr int HW    = 1024 * 1024;
constexpr int BATCH = 8;
constexpr int GROUPS_PER_IMG = HW / 4;     // 262144 = 2^18
constexpr int N_GROUPS = BATCH * GROUPS_PER_IMG;
constexpr unsigned LDS_BYTES = DIM3 * 4;   // 143748 B  (fits 160 KiB/CU)

// One dword per LUT texel: ch0 in bits[9:0], ch1 in bits[19:10], ch2 in bits[29:20],
// each quantized to 10-bit fixed point on [0,1].
__global__ __launch_bounds__(1024) void lut3d_apply_kernel(
    const float* __restrict__ lut,   // (3, 33, 33, 33)
    const float* __restrict__ x,     // (8, 3, 1024, 1024)
    float* __restrict__ out)         // (8, 3, 1024, 1024)
{
    extern __shared__ unsigned int sLut[];   // DIM3 dwords

    // ---- stage + quantize LUT into LDS (once per block) ----
    for (int i = threadIdx.x; i < DIM3; i += blockDim.x) {
        float v0 = lut[i];
        float v1 = lut[DIM3 + i];
        float v2 = lut[2 * DIM3 + i];
        unsigned q0 = (unsigned)(fminf(fmaxf(v0, 0.0f), 1.0f) * 1023.0f + 0.5f);
        unsigned q1 = (unsigned)(fminf(fmaxf(v1, 0.0f), 1.0f) * 1023.0f + 0.5f);
        unsigned q2 = (unsigned)(fminf(fmaxf(v2, 0.0f), 1.0f) * 1023.0f + 0.5f);
        sLut[i] = q0 | (q1 << 10) | (q2 << 20);
    }
    __syncthreads();

    const float invbin = 32.0f / 1.000001f;   // 1/binsize
    const float dq = 1.0f / 1023.0f;

    int stride = gridDim.x * blockDim.x;
    for (int g = blockIdx.x * blockDim.x + threadIdx.x; g < N_GROUPS; g += stride) {
        int b = g >> 18;                 // image index
        int q = g & (GROUPS_PER_IMG - 1);

        const float4* xr = reinterpret_cast<const float4*>(x + (size_t)(b * 3 + 0) * HW);
        const float4* xg = reinterpret_cast<const float4*>(x + (size_t)(b * 3 + 1) * HW);
        const float4* xb = reinterpret_cast<const float4*>(x + (size_t)(b * 3 + 2) * HW);

        float4 rv = xr[q];
        float4 gv = xg[q];
        float4 bv = xb[q];

        float rr[4] = {rv.x, rv.y, rv.z, rv.w};
        float gg[4] = {gv.x, gv.y, gv.z, gv.w};
        float bb[4] = {bv.x, bv.y, bv.z, bv.w};
        float o0[4], o1[4], o2[4];

#pragma unroll
        for (int i = 0; i < 4; ++i) {
            float tr = rr[i] * invbin;
            float tg = gg[i] * invbin;
            float tb = bb[i] * invbin;

            int ri = (int)floorf(tr);
            int gi = (int)floorf(tg);
            int bi = (int)floorf(tb);
            ri = ri < 0 ? 0 : (ri > DIM - 2 ? DIM - 2 : ri);
            gi = gi < 0 ? 0 : (gi > DIM - 2 ? DIM - 2 : gi);
            bi = bi < 0 ? 0 : (bi > DIM - 2 ? DIM - 2 : bi);

            float rd = tr - (float)ri;
            float gd = tg - (float)gi;
            float bd = tb - (float)bi;

            int base = bi * DIM2 + gi * DIM + ri;

            // 8 corner texels from LDS (adjacent r-pairs -> ds_read2_b32)
            unsigned c000 = sLut[base];
            unsigned c001 = sLut[base + 1];
            unsigned c010 = sLut[base + DIM];
            unsigned c011 = sLut[base + DIM + 1];
            unsigned c100 = sLut[base + DIM2];
            unsigned c101 = sLut[base + DIM2 + 1];
            unsigned c110 = sLut[base + DIM2 + DIM];
            unsigned c111 = sLut[base + DIM2 + DIM + 1];

            float wr1 = rd, wr0 = 1.0f - rd;
            float wg1 = gd, wg0 = 1.0f - gd;
            float wb1 = bd, wb0 = 1.0f - bd;

            float w000 = wb0 * wg0 * wr0;
            float w001 = wb0 * wg0 * wr1;
            float w010 = wb0 * wg1 * wr0;
            float w011 = wb0 * wg1 * wr1;
            float w100 = wb1 * wg0 * wr0;
            float w101 = wb1 * wg0 * wr1;
            float w110 = wb1 * wg1 * wr0;
            float w111 = wb1 * wg1 * wr1;

            // accumulate in quantized units, dequantize once at the end
            float a0 = w000 * (float)(c000 & 1023u) + w001 * (float)(c001 & 1023u)
                     + w010 * (float)(c010 & 1023u) + w011 * (float)(c011 & 1023u)
                     + w100 * (float)(c100 & 1023u) + w101 * (float)(c101 & 1023u)
                     + w110 * (float)(c110 & 1023u) + w111 * (float)(c111 & 1023u);

            float a1 = w000 * (float)((c000 >> 10) & 1023u) + w001 * (float)((c001 >> 10) & 1023u)
                     + w010 * (float)((c010 >> 10) & 1023u) + w011 * (float)((c011 >> 10) & 1023u)
                     + w100 * (float)((c100 >> 10) & 1023u) + w101 * (float)((c101 >> 10) & 1023u)
                     + w110 * (float)((c110 >> 10) & 1023u) + w111 * (float)((c111 >> 10) & 1023u);

            float a2 = w000 * (float)(c000 >> 20) + w001 * (float)(c001 >> 20)
                     + w010 * (float)(c010 >> 20) + w011 * (float)(c011 >> 20)
                     + w100 * (float)(c100 >> 20) + w101 * (float)(c101 >> 20)
                     + w110 * (float)(c110 >> 20) + w111 * (float)(c111 >> 20);

            o0[i] = a0 * dq;
            o1[i] = a1 * dq;
            o2[i] = a2 * dq;
        }

        float4* outr = reinterpret_cast<float4*>(out + (size_t)(b * 3 + 0) * HW);
        float4* outg = reinterpret_cast<float4*>(out + (size_t)(b * 3 + 1) * HW);
        float4* outb = reinterpret_cast<float4*>(out + (size_t)(b * 3 + 2) * HW);

        outr[q] = make_float4(o0[0], o0[1], o0[2], o0[3]);
        outg[q] = make_float4(o1[0], o1[1], o1[2], o1[3]);
        outb[q] = make_float4(o2[0], o2[1], o2[2], o2[3]);
    }
}

extern "C" void kernel_launch(void* const* d_in, const int* in_sizes, int n_in,
                              void* d_out, int out_size, void* d_ws, size_t ws_size,
                              hipStream_t stream) {
    const float* lut = (const float*)d_in[0];  // 3*33*33*33
    const float* x   = (const float*)d_in[1];  // 8*3*1024*1024
    float* out = (float*)d_out;

    // 140 KB LDS -> 1 block/CU; 1024 threads = 16 waves/CU; grid-stride loop.
    int block = 1024;
    int grid = 256;
    lut3d_apply_kernel<<<grid, block, LDS_BYTES, stream>>>(lut, x, out);
}